// Round 1
// baseline (2459.617 us; speedup 1.0000x reference)
//
#include <hip/hip_runtime.h>
#include <math.h>

#define D 768
#define DF4 192      // D/4
#define SEQ 128
#define BQ 32
#define TN 256       // docs per block tile
#define NCHUNK 24    // 768/32
#define NBK 64       // top-k blocks per row
#define TOPK 10

// ---------------- K1: mean over sequence ----------------
__global__ __launch_bounds__(256) void k_mean(const float* __restrict__ q,
                                              float* __restrict__ qmean) {
  int d = blockIdx.x * 256 + threadIdx.x;   // grid.x = 3 -> 768
  int b = blockIdx.y;
  if (d >= D) return;
  const float* p = q + (long)b * SEQ * D + d;
  float s = 0.f;
  #pragma unroll 8
  for (int i = 0; i < SEQ; ++i) s += p[(long)i * D];
  qmean[b * D + d] = s * (1.0f / SEQ);
}

// ---------------- K2: projection + bias + L2 normalize ----------------
__global__ __launch_bounds__(256) void k_proj(const float* __restrict__ qmean,
                                              const float* __restrict__ W,
                                              const float* __restrict__ bias,
                                              float* __restrict__ qnorm) {
  __shared__ float4 qm[DF4];
  __shared__ float outv[D];
  __shared__ float red[256];
  int b = blockIdx.x, t = threadIdx.x;
  for (int i = t; i < DF4; i += 256) qm[i] = ((const float4*)qmean)[b * DF4 + i];
  __syncthreads();
  float myout[3];
  #pragma unroll
  for (int i = 0; i < 3; ++i) {
    int j = t + i * 256;
    const float4* wr = (const float4*)W + (long)j * DF4;
    float a0 = 0.f, a1 = 0.f, a2 = 0.f, a3 = 0.f;
    for (int kk = 0; kk < DF4; ++kk) {
      float4 w = wr[kk]; float4 qv = qm[kk];
      a0 = fmaf(w.x, qv.x, a0); a1 = fmaf(w.y, qv.y, a1);
      a2 = fmaf(w.z, qv.z, a2); a3 = fmaf(w.w, qv.w, a3);
    }
    myout[i] = (a0 + a1) + (a2 + a3) + bias[j];
    outv[j] = myout[i];
  }
  float ss = myout[0]*myout[0] + myout[1]*myout[1] + myout[2]*myout[2];
  red[t] = ss;
  __syncthreads();
  for (int h = 128; h > 0; h >>= 1) {
    if (t < h) red[t] += red[t + h];
    __syncthreads();
  }
  float rn = 1.0f / fmaxf(sqrtf(red[0]), 1e-12f);
  #pragma unroll
  for (int i = 0; i < 3; ++i) {
    int j = t + i * 256;
    qnorm[b * D + j] = myout[i] * rn;
  }
}

// ---------------- K3: cosine scores (the big one) ----------------
// Block: 256 threads = 4 waves. Tile: 256 docs. Wave o handles q rows o*8..o*8+7.
// Lane handles docs {lane, lane+64, lane+128, lane+192} of the tile.
// LDS doc tile stored transposed-at-float4 with XOR swizzle: ldsD[kq][doc ^ kq].
__global__ __launch_bounds__(256, 4) void k_scores(const float* __restrict__ docs,
                                                   const float* __restrict__ qn,
                                                   float* __restrict__ outS, int N) {
  __shared__ float4 ldsD[8][TN];   // 32 KB
  __shared__ float4 ldsQ[BQ][8];   // 4 KB
  const int t = threadIdx.x;
  const int lane = t & 63;
  const int o = t >> 6;
  const int drow = t >> 3;   // 0..31
  const int kql = t & 7;     // 0..7
  const long tile0 = (long)blockIdx.x * TN;
  const float4* docs4 = (const float4*)docs;
  const float4* qn4 = (const float4*)qn;

  float acc[8][4];
  #pragma unroll
  for (int i = 0; i < 8; ++i)
    #pragma unroll
    for (int j = 0; j < 4; ++j) acc[i][j] = 0.f;
  float ssq[4] = {0.f, 0.f, 0.f, 0.f};

  float4 r[8];
  float4 qv;
  // prologue: load chunk 0
  #pragma unroll
  for (int i = 0; i < 8; ++i) {
    long g = tile0 + i * 32 + drow;
    if (g >= N) g = N - 1;
    r[i] = docs4[g * DF4 + kql];
  }
  qv = qn4[drow * DF4 + kql];

  for (int c = 0; c < NCHUNK; ++c) {
    __syncthreads();                       // LDS consumers of prev chunk done
    #pragma unroll
    for (int i = 0; i < 8; ++i) ldsD[kql][(i * 32 + drow) ^ kql] = r[i];
    ldsQ[drow][kql] = qv;
    __syncthreads();
    if (c + 1 < NCHUNK) {                  // issue next-chunk loads BEFORE compute
      const int off = (c + 1) * 8 + kql;
      #pragma unroll
      for (int i = 0; i < 8; ++i) {
        long g = tile0 + i * 32 + drow;
        if (g >= N) g = N - 1;
        r[i] = docs4[g * DF4 + off];
      }
      qv = qn4[drow * DF4 + off];
    }
    #pragma unroll
    for (int kq = 0; kq < 8; ++kq) {
      float4 dv[4];
      #pragma unroll
      for (int dj = 0; dj < 4; ++dj) {
        dv[dj] = ldsD[kq][(lane + dj * 64) ^ kq];
        ssq[dj] = fmaf(dv[dj].x, dv[dj].x, ssq[dj]);
        ssq[dj] = fmaf(dv[dj].y, dv[dj].y, ssq[dj]);
        ssq[dj] = fmaf(dv[dj].z, dv[dj].z, ssq[dj]);
        ssq[dj] = fmaf(dv[dj].w, dv[dj].w, ssq[dj]);
      }
      #pragma unroll
      for (int qi = 0; qi < 8; ++qi) {
        float4 q4 = ldsQ[o * 8 + qi][kq];
        #pragma unroll
        for (int dj = 0; dj < 4; ++dj) {
          acc[qi][dj] = fmaf(q4.x, dv[dj].x, acc[qi][dj]);
          acc[qi][dj] = fmaf(q4.y, dv[dj].y, acc[qi][dj]);
          acc[qi][dj] = fmaf(q4.z, dv[dj].z, acc[qi][dj]);
          acc[qi][dj] = fmaf(q4.w, dv[dj].w, acc[qi][dj]);
        }
      }
    }
  }
  #pragma unroll
  for (int dj = 0; dj < 4; ++dj) {
    long gd = tile0 + lane + dj * 64;
    if (gd < N) {
      float rn = 1.0f / fmaxf(sqrtf(ssq[dj]), 1e-12f);
      #pragma unroll
      for (int qi = 0; qi < 8; ++qi)
        outS[(long)(o * 8 + qi) * N + gd] = acc[qi][dj] * rn;
    }
  }
}

// ---------------- top-k helpers ----------------
// ranks-before comparator: higher score wins; tie -> smaller index (lax.top_k stable)
__device__ __forceinline__ void insert10(float v, float p, float bs[10], float bi[10]) {
  bool last = (v > bs[9]) || (v == bs[9] && p < bi[9]);
  if (!last) return;
  #pragma unroll
  for (int j = 9; j >= 1; --j) {     // static indices only (no scratch)
    bool bj  = (v > bs[j])   || (v == bs[j]   && p < bi[j]);
    bool bjm = (v > bs[j-1]) || (v == bs[j-1] && p < bi[j-1]);
    float ns = bj ? (bjm ? bs[j-1] : v) : bs[j];
    float ni = bj ? (bjm ? bi[j-1] : p) : bi[j];
    bs[j] = ns; bi[j] = ni;
  }
  bool b0 = (v > bs[0]) || (v == bs[0] && p < bi[0]);
  if (b0) { bs[0] = v; bi[0] = p; }
}

// ---------------- K4: per-(row, segment) top-10 ----------------
__global__ __launch_bounds__(256) void k_topblk(const float* __restrict__ scores,
                                                float2* __restrict__ btop, int N) {
  const int row = blockIdx.y, seg = blockIdx.x, t = threadIdx.x;
  const int per = (N + NBK - 1) / NBK;
  const int s0 = seg * per;
  const int s1 = (s0 + per < N) ? (s0 + per) : N;
  const float* rp = scores + (long)row * N;
  float bs[10], bi[10];
  #pragma unroll
  for (int k = 0; k < 10; ++k) { bs[k] = -INFINITY; bi[k] = 2.0e9f; }
  for (int p = s0 + t; p < s1; p += 256) insert10(rp[p], (float)p, bs, bi);

  __shared__ float ms[256][10];
  __shared__ float mi[256][10];
  #pragma unroll
  for (int k = 0; k < 10; ++k) { ms[t][k] = bs[k]; mi[t][k] = bi[k]; }
  __syncthreads();
  for (int h = 128; h > 0; h >>= 1) {
    if (t < h) {
      float os[10], oi[10];
      int x = 0, y = 0;
      #pragma unroll
      for (int k = 0; k < 10; ++k) {
        float sx = ms[t][x], sy = ms[t + h][y];
        float ix = mi[t][x], iy = mi[t + h][y];
        bool ta = (sx > sy) || (sx == sy && ix < iy);
        os[k] = ta ? sx : sy; oi[k] = ta ? ix : iy;
        x += ta ? 1 : 0; y += ta ? 0 : 1;
      }
      #pragma unroll
      for (int k = 0; k < 10; ++k) { ms[t][k] = os[k]; mi[t][k] = oi[k]; }
    }
    __syncthreads();
  }
  if (t == 0) {
    #pragma unroll
    for (int k = 0; k < 10; ++k)
      btop[((long)row * NBK + seg) * 10 + k] = make_float2(ms[0][k], mi[0][k]);
  }
}

// ---------------- K5: final merge per row, write indices as float ----------------
__global__ __launch_bounds__(256) void k_topfinal(const float2* __restrict__ btop,
                                                  float* __restrict__ outIdx) {
  const int row = blockIdx.x, t = threadIdx.x;
  const int M = NBK * 10;   // 640 candidates
  float bs[10], bi[10];
  #pragma unroll
  for (int k = 0; k < 10; ++k) { bs[k] = -INFINITY; bi[k] = 2.0e9f; }
  for (int p = t; p < M; p += 256) {
    float2 c = btop[(long)row * M + p];
    insert10(c.x, c.y, bs, bi);
  }
  __shared__ float ms[256][10];
  __shared__ float mi[256][10];
  #pragma unroll
  for (int k = 0; k < 10; ++k) { ms[t][k] = bs[k]; mi[t][k] = bi[k]; }
  __syncthreads();
  for (int h = 128; h > 0; h >>= 1) {
    if (t < h) {
      float os[10], oi[10];
      int x = 0, y = 0;
      #pragma unroll
      for (int k = 0; k < 10; ++k) {
        float sx = ms[t][x], sy = ms[t + h][y];
        float ix = mi[t][x], iy = mi[t + h][y];
        bool ta = (sx > sy) || (sx == sy && ix < iy);
        os[k] = ta ? sx : sy; oi[k] = ta ? ix : iy;
        x += ta ? 1 : 0; y += ta ? 0 : 1;
      }
      #pragma unroll
      for (int k = 0; k < 10; ++k) { ms[t][k] = os[k]; mi[t][k] = oi[k]; }
    }
    __syncthreads();
  }
  if (t == 0) {
    #pragma unroll
    for (int k = 0; k < 10; ++k) outIdx[row * TOPK + k] = mi[0][k];
  }
}

extern "C" void kernel_launch(void* const* d_in, const int* in_sizes, int n_in,
                              void* d_out, int out_size, void* d_ws, size_t ws_size,
                              hipStream_t stream) {
  const float* q    = (const float*)d_in[0];   // [32,128,768]
  const float* docs = (const float*)d_in[1];   // [N,768]
  const float* W    = (const float*)d_in[2];   // [768,768]
  const float* bias = (const float*)d_in[3];   // [768]
  const int B = in_sizes[0] / (SEQ * D);       // 32
  const int N = in_sizes[1] / D;               // 500000

  float* out    = (float*)d_out;
  float* outIdx = out;                          // [B*10] indices as float
  float* outS   = out + (long)B * TOPK;         // [B][N] scores

  float*  qmean = (float*)d_ws;                 // B*D
  float*  qnorm = qmean + (long)B * D;          // B*D
  float2* btop  = (float2*)(qnorm + (long)B * D); // B*NBK*10 pairs

  dim3 g1(3, B);
  k_mean<<<g1, 256, 0, stream>>>(q, qmean);
  k_proj<<<B, 256, 0, stream>>>(qmean, W, bias, qnorm);
  int ntiles = (N + TN - 1) / TN;
  k_scores<<<ntiles, 256, 0, stream>>>(docs, qnorm, outS, N);
  dim3 g4(NBK, B);
  k_topblk<<<g4, 256, 0, stream>>>(outS, btop, N);
  k_topfinal<<<B, 256, 0, stream>>>(btop, outIdx);
}

// Round 2
// 933.510 us; speedup vs baseline: 2.6348x; 2.6348x over previous
//
#include <hip/hip_runtime.h>
#include <math.h>

#define D 768
#define DF4 192      // D/4
#define SEQ 128
#define BQ 32
#define TN 256       // docs per block tile
#define NCHUNK 24    // 768/32
#define NBK 64       // top-k blocks per row
#define TOPK 10

// ---------------- K1: mean over sequence ----------------
__global__ __launch_bounds__(256) void k_mean(const float* __restrict__ q,
                                              float* __restrict__ qmean) {
  int d = blockIdx.x * 256 + threadIdx.x;   // grid.x = 3 -> 768
  int b = blockIdx.y;
  if (d >= D) return;
  const float* p = q + (long)b * SEQ * D + d;
  float s = 0.f;
  #pragma unroll 8
  for (int i = 0; i < SEQ; ++i) s += p[(long)i * D];
  qmean[b * D + d] = s * (1.0f / SEQ);
}

// ---------------- K2: projection + bias + L2 normalize ----------------
__global__ __launch_bounds__(256) void k_proj(const float* __restrict__ qmean,
                                              const float* __restrict__ W,
                                              const float* __restrict__ bias,
                                              float* __restrict__ qnorm) {
  __shared__ float4 qm[DF4];
  __shared__ float outv[D];
  __shared__ float red[256];
  int b = blockIdx.x, t = threadIdx.x;
  for (int i = t; i < DF4; i += 256) qm[i] = ((const float4*)qmean)[b * DF4 + i];
  __syncthreads();
  float myout[3];
  #pragma unroll
  for (int i = 0; i < 3; ++i) {
    int j = t + i * 256;
    const float4* wr = (const float4*)W + (long)j * DF4;
    float a0 = 0.f, a1 = 0.f, a2 = 0.f, a3 = 0.f;
    for (int kk = 0; kk < DF4; ++kk) {
      float4 w = wr[kk]; float4 qv = qm[kk];
      a0 = fmaf(w.x, qv.x, a0); a1 = fmaf(w.y, qv.y, a1);
      a2 = fmaf(w.z, qv.z, a2); a3 = fmaf(w.w, qv.w, a3);
    }
    myout[i] = (a0 + a1) + (a2 + a3) + bias[j];
    outv[j] = myout[i];
  }
  float ss = myout[0]*myout[0] + myout[1]*myout[1] + myout[2]*myout[2];
  red[t] = ss;
  __syncthreads();
  for (int h = 128; h > 0; h >>= 1) {
    if (t < h) red[t] += red[t + h];
    __syncthreads();
  }
  float rn = 1.0f / fmaxf(sqrtf(red[0]), 1e-12f);
  #pragma unroll
  for (int i = 0; i < 3; ++i) {
    int j = t + i * 256;
    qnorm[b * D + j] = myout[i] * rn;
  }
}

// ---------------- K3: cosine scores (the big one) ----------------
// Block: 256 threads = 4 waves. Tile: 256 docs. Wave o handles q rows o*8..o*8+7.
// Lane handles docs {lane, lane+64, lane+128, lane+192} of the tile.
// LDS doc tile stored transposed-at-float4 with XOR swizzle: ldsD[kq][doc ^ kq].
// __launch_bounds__(256, 2): budget 256 VGPRs -> no scratch spill (round-1
// (256,4) pinned VGPR=64 and spilled ~7.4 GB to scratch). Runtime occupancy
// will be VGPR-limited (~4 waves/SIMD) and LDS-limited (4 blocks/CU).
__global__ __launch_bounds__(256, 2) void k_scores(const float* __restrict__ docs,
                                                   const float* __restrict__ qn,
                                                   float* __restrict__ outS, int N) {
  __shared__ float4 ldsD[8][TN];   // 32 KB
  __shared__ float4 ldsQ[BQ][8];   // 4 KB
  const int t = threadIdx.x;
  const int lane = t & 63;
  const int o = t >> 6;
  const int drow = t >> 3;   // 0..31
  const int kql = t & 7;     // 0..7
  const long tile0 = (long)blockIdx.x * TN;
  const float4* docs4 = (const float4*)docs;
  const float4* qn4 = (const float4*)qn;

  float acc[8][4];
  #pragma unroll
  for (int i = 0; i < 8; ++i)
    #pragma unroll
    for (int j = 0; j < 4; ++j) acc[i][j] = 0.f;
  float ssq[4] = {0.f, 0.f, 0.f, 0.f};

  float4 r[8];
  float4 qv;
  // prologue: load chunk 0
  #pragma unroll
  for (int i = 0; i < 8; ++i) {
    long g = tile0 + i * 32 + drow;
    if (g >= N) g = N - 1;
    r[i] = docs4[g * DF4 + kql];
  }
  qv = qn4[drow * DF4 + kql];

  for (int c = 0; c < NCHUNK; ++c) {
    __syncthreads();                       // LDS consumers of prev chunk done
    #pragma unroll
    for (int i = 0; i < 8; ++i) ldsD[kql][(i * 32 + drow) ^ kql] = r[i];
    ldsQ[drow][kql] = qv;
    __syncthreads();
    if (c + 1 < NCHUNK) {                  // issue next-chunk loads BEFORE compute
      const int off = (c + 1) * 8 + kql;
      #pragma unroll
      for (int i = 0; i < 8; ++i) {
        long g = tile0 + i * 32 + drow;
        if (g >= N) g = N - 1;
        r[i] = docs4[g * DF4 + off];
      }
      qv = qn4[drow * DF4 + off];
    }
    #pragma unroll
    for (int kq = 0; kq < 8; ++kq) {
      float4 dv[4];
      #pragma unroll
      for (int dj = 0; dj < 4; ++dj) {
        dv[dj] = ldsD[kq][(lane + dj * 64) ^ kq];
        ssq[dj] = fmaf(dv[dj].x, dv[dj].x, ssq[dj]);
        ssq[dj] = fmaf(dv[dj].y, dv[dj].y, ssq[dj]);
        ssq[dj] = fmaf(dv[dj].z, dv[dj].z, ssq[dj]);
        ssq[dj] = fmaf(dv[dj].w, dv[dj].w, ssq[dj]);
      }
      #pragma unroll
      for (int qi = 0; qi < 8; ++qi) {
        float4 q4 = ldsQ[o * 8 + qi][kq];
        #pragma unroll
        for (int dj = 0; dj < 4; ++dj) {
          acc[qi][dj] = fmaf(q4.x, dv[dj].x, acc[qi][dj]);
          acc[qi][dj] = fmaf(q4.y, dv[dj].y, acc[qi][dj]);
          acc[qi][dj] = fmaf(q4.z, dv[dj].z, acc[qi][dj]);
          acc[qi][dj] = fmaf(q4.w, dv[dj].w, acc[qi][dj]);
        }
      }
    }
  }
  #pragma unroll
  for (int dj = 0; dj < 4; ++dj) {
    long gd = tile0 + lane + dj * 64;
    if (gd < N) {
      float rn = 1.0f / fmaxf(sqrtf(ssq[dj]), 1e-12f);
      #pragma unroll
      for (int qi = 0; qi < 8; ++qi)
        outS[(long)(o * 8 + qi) * N + gd] = acc[qi][dj] * rn;
    }
  }
}

// ---------------- top-k helpers ----------------
// ranks-before comparator: higher score wins; tie -> smaller index (lax.top_k stable)
__device__ __forceinline__ void insert10(float v, float p, float bs[10], float bi[10]) {
  bool last = (v > bs[9]) || (v == bs[9] && p < bi[9]);
  if (!last) return;
  #pragma unroll
  for (int j = 9; j >= 1; --j) {     // static indices only (no scratch)
    bool bj  = (v > bs[j])   || (v == bs[j]   && p < bi[j]);
    bool bjm = (v > bs[j-1]) || (v == bs[j-1] && p < bi[j-1]);
    float ns = bj ? (bjm ? bs[j-1] : v) : bs[j];
    float ni = bj ? (bjm ? bi[j-1] : p) : bi[j];
    bs[j] = ns; bi[j] = ni;
  }
  bool b0 = (v > bs[0]) || (v == bs[0] && p < bi[0]);
  if (b0) { bs[0] = v; bi[0] = p; }
}

// ---------------- K4: per-(row, segment) top-10 ----------------
__global__ __launch_bounds__(256) void k_topblk(const float* __restrict__ scores,
                                                float2* __restrict__ btop, int N) {
  const int row = blockIdx.y, seg = blockIdx.x, t = threadIdx.x;
  const int per = (N + NBK - 1) / NBK;
  const int s0 = seg * per;
  const int s1 = (s0 + per < N) ? (s0 + per) : N;
  const float* rp = scores + (long)row * N;
  float bs[10], bi[10];
  #pragma unroll
  for (int k = 0; k < 10; ++k) { bs[k] = -INFINITY; bi[k] = 2.0e9f; }
  for (int p = s0 + t; p < s1; p += 256) insert10(rp[p], (float)p, bs, bi);

  __shared__ float ms[256][10];
  __shared__ float mi[256][10];
  #pragma unroll
  for (int k = 0; k < 10; ++k) { ms[t][k] = bs[k]; mi[t][k] = bi[k]; }
  __syncthreads();
  for (int h = 128; h > 0; h >>= 1) {
    if (t < h) {
      float os[10], oi[10];
      int x = 0, y = 0;
      #pragma unroll
      for (int k = 0; k < 10; ++k) {
        float sx = ms[t][x], sy = ms[t + h][y];
        float ix = mi[t][x], iy = mi[t + h][y];
        bool ta = (sx > sy) || (sx == sy && ix < iy);
        os[k] = ta ? sx : sy; oi[k] = ta ? ix : iy;
        x += ta ? 1 : 0; y += ta ? 0 : 1;
      }
      #pragma unroll
      for (int k = 0; k < 10; ++k) { ms[t][k] = os[k]; mi[t][k] = oi[k]; }
    }
    __syncthreads();
  }
  if (t == 0) {
    #pragma unroll
    for (int k = 0; k < 10; ++k)
      btop[((long)row * NBK + seg) * 10 + k] = make_float2(ms[0][k], mi[0][k]);
  }
}

// ---------------- K5: final merge per row, write indices as float ----------------
__global__ __launch_bounds__(256) void k_topfinal(const float2* __restrict__ btop,
                                                  float* __restrict__ outIdx) {
  const int row = blockIdx.x, t = threadIdx.x;
  const int M = NBK * 10;   // 640 candidates
  float bs[10], bi[10];
  #pragma unroll
  for (int k = 0; k < 10; ++k) { bs[k] = -INFINITY; bi[k] = 2.0e9f; }
  for (int p = t; p < M; p += 256) {
    float2 c = btop[(long)row * M + p];
    insert10(c.x, c.y, bs, bi);
  }
  __shared__ float ms[256][10];
  __shared__ float mi[256][10];
  #pragma unroll
  for (int k = 0; k < 10; ++k) { ms[t][k] = bs[k]; mi[t][k] = bi[k]; }
  __syncthreads();
  for (int h = 128; h > 0; h >>= 1) {
    if (t < h) {
      float os[10], oi[10];
      int x = 0, y = 0;
      #pragma unroll
      for (int k = 0; k < 10; ++k) {
        float sx = ms[t][x], sy = ms[t + h][y];
        float ix = mi[t][x], iy = mi[t + h][y];
        bool ta = (sx > sy) || (sx == sy && ix < iy);
        os[k] = ta ? sx : sy; oi[k] = ta ? ix : iy;
        x += ta ? 1 : 0; y += ta ? 0 : 1;
      }
      #pragma unroll
      for (int k = 0; k < 10; ++k) { ms[t][k] = os[k]; mi[t][k] = oi[k]; }
    }
    __syncthreads();
  }
  if (t == 0) {
    #pragma unroll
    for (int k = 0; k < 10; ++k) outIdx[row * TOPK + k] = mi[0][k];
  }
}

extern "C" void kernel_launch(void* const* d_in, const int* in_sizes, int n_in,
                              void* d_out, int out_size, void* d_ws, size_t ws_size,
                              hipStream_t stream) {
  const float* q    = (const float*)d_in[0];   // [32,128,768]
  const float* docs = (const float*)d_in[1];   // [N,768]
  const float* W    = (const float*)d_in[2];   // [768,768]
  const float* bias = (const float*)d_in[3];   // [768]
  const int B = in_sizes[0] / (SEQ * D);       // 32
  const int N = in_sizes[1] / D;               // 500000

  float* out    = (float*)d_out;
  float* outIdx = out;                          // [B*10] indices as float
  float* outS   = out + (long)B * TOPK;         // [B][N] scores

  float*  qmean = (float*)d_ws;                 // B*D
  float*  qnorm = qmean + (long)B * D;          // B*D
  float2* btop  = (float2*)(qnorm + (long)B * D); // B*NBK*10 pairs

  dim3 g1(3, B);
  k_mean<<<g1, 256, 0, stream>>>(q, qmean);
  k_proj<<<B, 256, 0, stream>>>(qmean, W, bias, qnorm);
  int ntiles = (N + TN - 1) / TN;
  k_scores<<<ntiles, 256, 0, stream>>>(docs, qnorm, outS, N);
  dim3 g4(NBK, B);
  k_topblk<<<g4, 256, 0, stream>>>(outS, btop, N);
  k_topfinal<<<B, 256, 0, stream>>>(btop, outIdx);
}